// Round 5
// baseline (134.145 us; speedup 1.0000x reference)
//
#include <hip/hip_runtime.h>
#include <math.h>

#define EPS 1e-7f

constexpr int B = 16, L = 1024, D = 256, P = 20;
constexpr int LD = L * D;     // 262144
constexpr int DD = D * D;     // 65536

typedef __attribute__((ext_vector_type(8))) _Float16 f16x8;
typedef __attribute__((ext_vector_type(4))) float f32x4;

// ---------------------------------------------------------------------------
// 3-kernel pipeline.  ws layout (float slots):
//   tp  @0        131072   fp32 [32][B][D]   t partials (from k_prep2)
//   CT  @131072   2097152  fp16 [B][D][L]    s2*sqrt(invn2), transposed
//   Gf  @2228224  524288   fp16 [B][D][D]    gram
// Round 5: all three kernels were latency-bound (MfmaUtil 1.7%, VALU 29%,
// HBM 5.7% on k_mav_out).  Fix = kill barrier-lockstep staging:
//   - gram32: MFMA fragments loaded DIRECTLY from global CT (L2/L3-resident);
//     no As/Bs, no in-loop barriers (8 -> 0), keep K-split + LDS reduce.
//   - mav_out: B fragments direct from global Gf; A fragments hoisted to
//     registers; barriers 11 -> 4; LDS 69 -> 55 KB.
//   - prep2: 512 threads/block (16 waves/CU vs 8).
// ---------------------------------------------------------------------------

__device__ inline unsigned short f2h(float x) {
    _Float16 h = (_Float16)x;
    union { _Float16 h; unsigned short u; } c; c.h = h; return c.u;
}
__device__ inline float h2f(unsigned short u) {
    union { unsigned short u; _Float16 h; } c; c.u = u; return (float)c.h;
}

// K1: one pass over s2.  Block = 32 full rows (b, m0..m0+31), 512 threads.
// Computes invn2 locally, emits tp partials and transposed fp16 CT.  Grid 512.
__global__ __launch_bounds__(512) void k_prep2(const float* __restrict__ s2,
                                               float* __restrict__ tp,
                                               unsigned short* __restrict__ CT) {
    __shared__ float tile[32][257];
    __shared__ float wiv[32];   // invn2 = 1/norm
    __shared__ float wsq[32];   // sqrt(invn2)
    __shared__ float tpp[2][256];
    int tid = threadIdx.x;
    int b   = blockIdx.x >> 5, mt = blockIdx.x & 31;
    int m0  = mt * 32;
    {
        int r = tid >> 4, c0 = (tid & 15) * 16;   // 32 rows x 16 thr x 16 floats
        const float* gp = s2 + (size_t)b * LD + (size_t)(m0 + r) * D + c0;
        float4 v[4];
#pragma unroll
        for (int q = 0; q < 4; ++q) v[q] = ((const float4*)gp)[q];
#pragma unroll
        for (int q = 0; q < 4; ++q) *(float4*)&tile[r][c0 + q * 4] = v[q];
    }
    __syncthreads();
    {
        int r = tid >> 4, seg = tid & 15;
        float s = 0.f;
#pragma unroll
        for (int k = 0; k < 16; ++k) { float v = tile[r][seg * 16 + k]; s += v * v; }
#pragma unroll
        for (int o = 8; o; o >>= 1) s += __shfl_down(s, o, 16);
        if (seg == 0) {
            float iv = 1.0f / sqrtf(fmaxf(s, EPS));
            wiv[r] = iv;
            wsq[r] = sqrtf(iv);
        }
    }
    __syncthreads();
    {
        int dc = tid & 255, h = tid >> 8;      // d-column, m-half
        float tpart = 0.f;
        union { unsigned short us[16]; uint4 q[2]; } ph;
#pragma unroll
        for (int mm = 0; mm < 16; ++mm) {
            int m = h * 16 + mm;
            float v = tile[m][dc];
            tpart += v * wiv[m];
            ph.us[mm] = f2h(v * wsq[m]);
        }
        tpp[h][dc] = tpart;
        size_t o = (size_t)b * LD + (size_t)dc * L + m0 + h * 16;
        *(uint4*)(CT + o) = ph.q[0]; *(uint4*)(CT + o + 8) = ph.q[1];
    }
    __syncthreads();
    if (tid < 256)
        tp[(size_t)(mt * B + b) * D + tid] = tpp[0][tid] + tpp[1][tid];
}

// K2: gram G = C C^T, fp16 MFMA fragments loaded DIRECTLY from global CT
// (no LDS staging, no in-loop barriers).  32x32 output tile; 4 waves split
// K contiguously (wave w: k in [w*256, w*256+256)); LDS reduce at the end.
// Grid = 16 b x 8 ti x 8 tj = 1024 blocks.
__global__ __launch_bounds__(256) void k_gram32(const unsigned short* __restrict__ CT,
                                                unsigned short* __restrict__ Gf) {
    __shared__ float red[4 * 32 * 33];     // 16.9 KB
    int tid  = threadIdx.x;
    int b    = blockIdx.x >> 6;
    int ti   = (blockIdx.x >> 3) & 7;
    int tj   = blockIdx.x & 7;
    int wave = tid >> 6, lane = tid & 63;
    int lr   = lane & 15, lq = lane >> 4;

    const unsigned short* baseA = CT + (size_t)b * LD + (size_t)(ti * 32 + lr) * L;
    const unsigned short* baseB = CT + (size_t)b * LD + (size_t)(tj * 32 + lr) * L;

    f32x4 acc[2][2];
#pragma unroll
    for (int i = 0; i < 2; ++i)
#pragma unroll
        for (int j = 0; j < 2; ++j) acc[i][j] = (f32x4){0.f, 0.f, 0.f, 0.f};

    int k0 = wave * 256 + lq * 8;
#pragma unroll 4
    for (int ks = 0; ks < 8; ++ks) {
        int ko = k0 + ks * 32;
        f16x8 af[2], bf[2];
        af[0] = *(const f16x8*)(baseA + ko);
        af[1] = *(const f16x8*)(baseA + 16 * L + ko);
        bf[0] = *(const f16x8*)(baseB + ko);
        bf[1] = *(const f16x8*)(baseB + 16 * L + ko);
#pragma unroll
        for (int i = 0; i < 2; ++i)
#pragma unroll
            for (int j = 0; j < 2; ++j)
                acc[i][j] = __builtin_amdgcn_mfma_f32_16x16x32_f16(af[i], bf[j], acc[i][j], 0, 0, 0);
    }
#pragma unroll
    for (int i = 0; i < 2; ++i)
#pragma unroll
        for (int j = 0; j < 2; ++j)
#pragma unroll
            for (int r = 0; r < 4; ++r) {
                int row = i * 16 + lq * 4 + r, col = j * 16 + lr;
                red[wave * 1056 + row * 33 + col] = acc[i][j][r];
            }
    __syncthreads();
#pragma unroll
    for (int k = 0; k < 4; ++k) {
        int e = tid + k * 256;
        int row = e >> 5, col = e & 31;
        float s = red[row * 33 + col] + red[1056 + row * 33 + col] +
                  red[2112 + row * 33 + col] + red[3168 + row * 33 + col];
        Gf[(size_t)b * DD + (size_t)(ti * 32 + row) * D + tj * 32 + col] = f2h(s);
    }
}

// K3: FUSED  mav = s1 @ G  +  perspective-cosine output.
// Block = 32 l rows, 512 threads (8 waves).  B fragments direct from global
// Gf (L2-resident); A fragments hoisted into registers; 4 barriers total.
// LDS ~55 KB -> 2 blocks/CU.  Grid = 16 b x 32 lt = 512.
__global__ __launch_bounds__(512) void k_mav_out(const float* __restrict__ s1,
                                                 const float* __restrict__ tp,
                                                 const unsigned short* __restrict__ Gf,
                                                 const float* __restrict__ kern,
                                                 float* __restrict__ out) {
    __shared__ short As[32 * 264];   // s1 fp16, resident through epilogue
    __shared__ short Ms[32 * 264];   // mav fp16
    __shared__ float k2s[P * 264];   // kernel^2, stride 264
    __shared__ float ts[D];
    __shared__ float sgnS[32];
    int tid  = threadIdx.x;
    int b    = blockIdx.x >> 5, lt = blockIdx.x & 31;
    int l0   = lt * 32;
    int wave = tid >> 6, lane = tid & 63;
    int lr   = lane & 15, lq = lane >> 4;

    // (a) t[d] reduce + k2s stage
    if (tid < 256) {
        float a = 0.f;
#pragma unroll
        for (int mc = 0; mc < 32; ++mc) a += tp[(size_t)(mc * B + b) * D + tid];
        ts[tid] = a;
    }
    {
        int d = tid & 255, ph = tid >> 8;
#pragma unroll
        for (int i = 0; i < 10; ++i) {
            int p = i * 2 + ph;
            float v = kern[p * D + d];
            k2s[p * 264 + d] = v * v;
        }
    }
    __syncthreads();

    // (b) stage s1 -> As fp16; per-row sign of (s1.t + EPS*n1)
    {
        int r = tid >> 4, seg = tid & 15;      // 32 rows x 16 threads x 16 floats
        const float* gp = s1 + (size_t)(b * L + l0 + r) * D + seg * 16;
        float up = 0.f, sq = 0.f;
        union { unsigned short us[16]; uint4 q[2]; } hb;
#pragma unroll
        for (int q4 = 0; q4 < 4; ++q4) {
            float4 v = ((const float4*)gp)[q4];
            int td = seg * 16 + q4 * 4;
            up += v.x * ts[td] + v.y * ts[td + 1] + v.z * ts[td + 2] + v.w * ts[td + 3];
            sq += v.x * v.x + v.y * v.y + v.z * v.z + v.w * v.w;
            hb.us[q4 * 4 + 0] = f2h(v.x); hb.us[q4 * 4 + 1] = f2h(v.y);
            hb.us[q4 * 4 + 2] = f2h(v.z); hb.us[q4 * 4 + 3] = f2h(v.w);
        }
        short* la = &As[r * 264 + seg * 16];
        ((uint4*)la)[0] = hb.q[0]; ((uint4*)la)[1] = hb.q[1];
#pragma unroll
        for (int o = 8; o; o >>= 1) { up += __shfl_down(up, o, 16); sq += __shfl_down(sq, o, 16); }
        if (seg == 0) {
            float n1v = sqrtf(fmaxf(sq, EPS));
            sgnS[r] = up + EPS * n1v;          // only the sign is ever used
        }
    }
    __syncthreads();                            // As ready

    // (c) GEMM: wave (wlr, wnc); A frags hoisted, B direct from global Gf
    {
        int wlr = (wave >> 2) * 16;
        int wnc = (wave & 3) * 16;
        f16x8 af[8];
#pragma unroll
        for (int ks = 0; ks < 8; ++ks)
            af[ks] = *(const f16x8*)&As[(wlr + lr) * 264 + ks * 32 + lq * 8];
        const unsigned short* gb0 = Gf + (size_t)b * DD + (size_t)(wnc + lr) * D + lq * 8;
#pragma unroll 1
        for (int nh = 0; nh < 4; ++nh) {
            const unsigned short* gb = gb0 + (size_t)(nh * 64) * D;
            f32x4 acc = (f32x4){0.f, 0.f, 0.f, 0.f};
#pragma unroll
            for (int ks = 0; ks < 8; ++ks) {
                f16x8 bf = *(const f16x8*)(gb + ks * 32);
                acc = __builtin_amdgcn_mfma_f32_16x16x32_f16(af[ks], bf, acc, 0, 0, 0);
            }
#pragma unroll
            for (int r4 = 0; r4 < 4; ++r4)
                Ms[(wlr + lq * 4 + r4) * 264 + nh * 64 + wnc + lr] = f2h(acc[r4]);
        }
    }
    __syncthreads();                            // Ms complete

    // (d) epilogue: 4 rows/wave, 5 p-groups
    int dg = lane & 15, ps = lane >> 4;
#pragma unroll 1
    for (int rl = 0; rl < 4; ++rl) {
        int l = wave * 4 + rl;
        float4 sm[4], ss[4], mm[4];
#pragma unroll
        for (int j = 0; j < 4; ++j) {
            ushort4 h4 = *(const ushort4*)&As[l * 264 + dg * 4 + j * 64];
            ushort4 m4 = *(const ushort4*)&Ms[l * 264 + dg * 4 + j * 64];
            float4 sv, mv;
            sv.x = h2f(h4.x); sv.y = h2f(h4.y); sv.z = h2f(h4.z); sv.w = h2f(h4.w);
            mv.x = h2f(m4.x); mv.y = h2f(m4.y); mv.z = h2f(m4.z); mv.w = h2f(m4.w);
            sm[j].x = sv.x * mv.x; sm[j].y = sv.y * mv.y; sm[j].z = sv.z * mv.z; sm[j].w = sv.w * mv.w;
            ss[j].x = sv.x * sv.x; ss[j].y = sv.y * sv.y; ss[j].z = sv.z * sv.z; ss[j].w = sv.w * sv.w;
            mm[j].x = mv.x * mv.x; mm[j].y = mv.y * mv.y; mm[j].z = mv.z * mv.z; mm[j].w = mv.w * mv.w;
        }
        float sgn = (sgnS[l] < 0.f) ? -1.f : 1.f;
#pragma unroll
        for (int tI = 0; tI < 5; ++tI) {
            int p = ps + tI * 4;
            float na = 0.f, nb = 0.f, nc = 0.f;
#pragma unroll
            for (int j = 0; j < 4; ++j) {
                float4 kv = *(const float4*)&k2s[p * 264 + j * 64 + dg * 4];
                na += sm[j].x * kv.x + sm[j].y * kv.y + sm[j].z * kv.z + sm[j].w * kv.w;
                nb += ss[j].x * kv.x + ss[j].y * kv.y + ss[j].z * kv.z + ss[j].w * kv.w;
                nc += mm[j].x * kv.x + mm[j].y * kv.y + mm[j].z * kv.z + mm[j].w * kv.w;
            }
#pragma unroll
            for (int o = 8; o; o >>= 1) {
                na += __shfl_down(na, o, 16);
                nb += __shfl_down(nb, o, 16);
                nc += __shfl_down(nc, o, 16);
            }
            if (dg == 0) {
                out[(size_t)(b * L + l0 + l) * P + p] =
                    sgn * na * rsqrtf(fmaxf(nb, EPS)) * rsqrtf(fmaxf(nc, EPS));
            }
        }
    }
}

extern "C" void kernel_launch(void* const* d_in, const int* in_sizes, int n_in,
                              void* d_out, int out_size, void* d_ws, size_t ws_size,
                              hipStream_t stream) {
    const float* s1   = (const float*)d_in[0];
    const float* s2   = (const float*)d_in[1];
    const float* kern = (const float*)d_in[2];
    float* out = (float*)d_out;
    float* ws  = (float*)d_ws;

    float* tp = ws;                                            // 131072 f
    unsigned short* CT = (unsigned short*)(ws + 131072);       // 4194304 h
    unsigned short* Gf = (unsigned short*)(ws + 2228224);      // 1048576 h

    k_prep2<<<512, 512, 0, stream>>>(s2, tp, CT);
    k_gram32<<<1024, 256, 0, stream>>>(CT, Gf);
    k_mav_out<<<512, 512, 0, stream>>>(s1, tp, Gf, kern, out);
}

// Round 6
// 124.212 us; speedup vs baseline: 1.0800x; 1.0800x over previous
//
#include <hip/hip_runtime.h>
#include <math.h>

#define EPS 1e-7f

constexpr int B = 16, L = 1024, D = 256, P = 20;
constexpr int LD = L * D;     // 262144
constexpr int DD = D * D;     // 65536

typedef __attribute__((ext_vector_type(8))) _Float16 f16x8;
typedef __attribute__((ext_vector_type(4))) float f32x4;

// ---------------------------------------------------------------------------
// ws layout (float slots):
//   tp  @0        131072   fp32 [32][B][D]   t partials
//   CT  @131072   2097152  fp16 [B][D][L]    s2*sqrt(invn2), transposed
//   Gf  @2228224  524288   fp16 [B][D][D]    gram (symmetric)
// Round 6: coalescing + symmetry + finer mav blocks.
//   - prep2: lane-linear s2 loads; CT written as 64B row-chunks (was 16B
//     scatter at 2KB stride).
//   - gram: LDS staging (coalesced 512B/row), ti<=tj only (36 tiles),
//     writes tile + transpose.  Grid 576.
//   - mav: 1024 x 256-thr blocks (16 rows, 39KB LDS -> 4 blocks/CU),
//     s1 loads issued before ts/k2s phase.
// ---------------------------------------------------------------------------

__device__ inline unsigned short f2h(float x) {
    _Float16 h = (_Float16)x;
    union { _Float16 h; unsigned short u; } c; c.h = h; return c.u;
}
__device__ inline float h2f(unsigned short u) {
    union { unsigned short u; _Float16 h; } c; c.u = u; return (float)c.h;
}

// K1: one pass over s2.  Block = 32 rows (b, m0..m0+31), 512 threads.
__global__ __launch_bounds__(512) void k_prep2(const float* __restrict__ s2,
                                               float* __restrict__ tp,
                                               unsigned short* __restrict__ CT) {
    __shared__ float tile[32][260];   // 260: 16B-aligned rows, good banks
    __shared__ float wiv[32];
    __shared__ float wsq[32];
    __shared__ float tpp[2][256];
    int tid = threadIdx.x;
    int b   = blockIdx.x >> 5, mt = blockIdx.x & 31;
    int m0  = mt * 32;
    const float* gbase = s2 + (size_t)b * LD + (size_t)m0 * D;
    // coalesced load: 2048 float4 chunks, lane-linear (1KB/instr contiguous)
    float4 v[4];
#pragma unroll
    for (int i = 0; i < 4; ++i) {
        int u = tid + i * 512;
        v[i] = *(const float4*)(gbase + (size_t)(u >> 6) * D + (u & 63) * 4);
    }
#pragma unroll
    for (int i = 0; i < 4; ++i) {
        int u = tid + i * 512;
        *(float4*)&tile[u >> 6][(u & 63) * 4] = v[i];
    }
    __syncthreads();
    // norms: 16 threads/row x 16 floats
    {
        int r = tid >> 4, seg = tid & 15;
        float s = 0.f;
#pragma unroll
        for (int q = 0; q < 4; ++q) {
            float4 x = *(const float4*)&tile[r][seg * 16 + q * 4];
            s += x.x * x.x + x.y * x.y + x.z * x.z + x.w * x.w;
        }
#pragma unroll
        for (int o = 8; o; o >>= 1) s += __shfl_down(s, o, 16);
        if (seg == 0) {
            float iv = 1.0f / sqrtf(fmaxf(s, EPS));
            wiv[r] = iv;
            wsq[r] = sqrtf(iv);
        }
    }
    __syncthreads();
    // tp partials (per d-column, m-half split)
    {
        int dc = tid & 255, h = tid >> 8;
        float tpart = 0.f;
#pragma unroll
        for (int mm = 0; mm < 16; ++mm) {
            int m = h * 16 + mm;
            tpart += tile[m][dc] * wiv[m];
        }
        tpp[h][dc] = tpart;
    }
    // CT write: 1024 uint4 chunks; 4 consecutive lanes cover one 64B row-chunk
    {
        unsigned short* cbase = CT + (size_t)b * LD + m0;
#pragma unroll
        for (int i = 0; i < 2; ++i) {
            int u = tid + i * 512;
            int d = u >> 2, c = u & 3;
            union { unsigned short us[8]; uint4 q; } pk;
#pragma unroll
            for (int k = 0; k < 8; ++k) {
                int m = c * 8 + k;
                pk.us[k] = f2h(tile[m][d] * wsq[m]);
            }
            *(uint4*)(cbase + (size_t)d * L + c * 8) = pk.q;
        }
    }
    __syncthreads();
    if (tid < 256)
        tp[(size_t)(mt * B + b) * D + tid] = tpp[0][tid] + tpp[1][tid];
}

// K2: gram G = C C^T (fp16 MFMA, fp32 accum), SYMMETRIC: only ti<=tj tiles
// (36 of 64), each written twice (tile + transpose).  4 waves split K,
// LDS staging with coalesced 512B-row loads, LDS reduce at end.
// Grid = 16 b x 36 = 576 blocks, 256 threads.
__global__ __launch_bounds__(256) void k_gram32(const unsigned short* __restrict__ CT,
                                                unsigned short* __restrict__ Gf) {
    __shared__ short smem[2 * 32 * 264];   // As @0, Bs @32*264; red overlays
    short* As = smem;
    short* Bs = smem + 32 * 264;
    int tid = threadIdx.x;
    int b   = blockIdx.x / 36;
    int t   = blockIdx.x - b * 36;
    int ti = 0, rem = t;
    while (rem >= 8 - ti) { rem -= 8 - ti; ++ti; }
    int tj = ti + rem;
    bool diag = (ti == tj);
    int wave = tid >> 6, lane = tid & 63;
    int lr = lane & 15, lq = lane >> 4;

    const unsigned short* rowA = CT + (size_t)b * LD + (size_t)(ti * 32) * L;
    const unsigned short* rowB = CT + (size_t)b * LD + (size_t)(tj * 32) * L;

    f32x4 acc[2][2];
#pragma unroll
    for (int i = 0; i < 2; ++i)
#pragma unroll
        for (int j = 0; j < 2; ++j) acc[i][j] = (f32x4){0.f, 0.f, 0.f, 0.f};

#pragma unroll 1
    for (int kb = 0; kb < 4; ++kb) {
        int koff = kb * 256;
        __syncthreads();
        {
            // 1024 uint4 per buffer; 32 lanes cover one 512B row-chunk
#pragma unroll
            for (int i = 0; i < 4; ++i) {
                int u = tid + i * 256;
                int row = u >> 5, c = u & 31;
                *(uint4*)&As[row * 264 + c * 8] =
                    *(const uint4*)(rowA + (size_t)row * L + koff + c * 8);
            }
            if (!diag) {
#pragma unroll
                for (int i = 0; i < 4; ++i) {
                    int u = tid + i * 256;
                    int row = u >> 5, c = u & 31;
                    *(uint4*)&Bs[row * 264 + c * 8] =
                        *(const uint4*)(rowB + (size_t)row * L + koff + c * 8);
                }
            }
        }
        __syncthreads();
        const short* Bp = diag ? As : Bs;
#pragma unroll
        for (int kk = 0; kk < 2; ++kk) {
            int ks = wave * 2 + kk;
            f16x8 af[2], bf[2];
#pragma unroll
            for (int i = 0; i < 2; ++i)
                af[i] = *(const f16x8*)&As[(i * 16 + lr) * 264 + ks * 32 + lq * 8];
#pragma unroll
            for (int j = 0; j < 2; ++j)
                bf[j] = *(const f16x8*)&Bp[(j * 16 + lr) * 264 + ks * 32 + lq * 8];
#pragma unroll
            for (int i = 0; i < 2; ++i)
#pragma unroll
                for (int j = 0; j < 2; ++j)
                    acc[i][j] = __builtin_amdgcn_mfma_f32_16x16x32_f16(af[i], bf[j], acc[i][j], 0, 0, 0);
        }
    }
    __syncthreads();                       // MFMA reads done -> reuse smem
    float* red = (float*)smem;             // [4][32][33]
#pragma unroll
    for (int i = 0; i < 2; ++i)
#pragma unroll
        for (int j = 0; j < 2; ++j)
#pragma unroll
            for (int r = 0; r < 4; ++r) {
                int row = i * 16 + lq * 4 + r, col = j * 16 + lr;
                red[wave * 1056 + row * 33 + col] = acc[i][j][r];
            }
    __syncthreads();
    unsigned short* gout = Gf + (size_t)b * DD;
#pragma unroll
    for (int k = 0; k < 4; ++k) {
        int e = tid + k * 256;
        int row = e >> 5, col = e & 31;
        float s = red[row * 33 + col] + red[1056 + row * 33 + col] +
                  red[2112 + row * 33 + col] + red[3168 + row * 33 + col];
        gout[(size_t)(ti * 32 + row) * D + tj * 32 + col] = f2h(s);
    }
    if (!diag) {
#pragma unroll
        for (int k = 0; k < 4; ++k) {
            int e = tid + k * 256;
            int r2 = e >> 5, c2 = e & 31;
            float s = red[c2 * 33 + r2] + red[1056 + c2 * 33 + r2] +
                      red[2112 + c2 * 33 + r2] + red[3168 + c2 * 33 + r2];
            gout[(size_t)(tj * 32 + r2) * D + ti * 32 + c2] = f2h(s);
        }
    }
}

// K3: FUSED mav = s1 @ G + perspective-cosine output.
// Block = 16 l rows, 256 threads (4 waves), LDS 39KB -> 4 blocks/CU.
// Grid = 16 b x 64 lt = 1024.  B fragments direct from L2-resident Gf.
__global__ __launch_bounds__(256) void k_mav_out(const float* __restrict__ s1,
                                                 const float* __restrict__ tp,
                                                 const unsigned short* __restrict__ Gf,
                                                 const float* __restrict__ kern,
                                                 float* __restrict__ out) {
    __shared__ short As[16 * 264];
    __shared__ short Ms[16 * 264];
    __shared__ float k2s[P * 264];
    __shared__ float ts[256];
    __shared__ float sgnS[16];
    int tid  = threadIdx.x;
    int b    = blockIdx.x >> 6, lt = blockIdx.x & 63;
    int l0   = lt * 16;
    int wave = tid >> 6, lane = tid & 63;
    int lr   = lane & 15, lq = lane >> 4;

    // issue s1 loads early (hide HBM latency under phase a)
    float4 sv[4];
    const float* s1b = s1 + (size_t)(b * L + l0) * D;
#pragma unroll
    for (int i = 0; i < 4; ++i) {
        int u = tid + i * 256;
        sv[i] = *(const float4*)(s1b + (size_t)(u >> 6) * D + (u & 63) * 4);
    }

    // (a) ts reduce + k2s stage
    {
        float a = 0.f;
#pragma unroll
        for (int mc = 0; mc < 32; ++mc) a += tp[(size_t)(mc * B + b) * D + tid];
        ts[tid] = a;
    }
#pragma unroll
    for (int p = 0; p < P; ++p) {
        float v = kern[p * D + tid];
        k2s[p * 264 + tid] = v * v;
    }
    __syncthreads();

    // (b) As (fp16) + per-row sign of (s1.t + EPS*n1); row = wave + 4i
    {
        float up[4], sq[4];
#pragma unroll
        for (int i = 0; i < 4; ++i) {
            int u = tid + i * 256;
            int c = u & 63;
            float4 x = sv[i];
            float4 tv = *(const float4*)(ts + c * 4);
            up[i] = x.x * tv.x + x.y * tv.y + x.z * tv.z + x.w * tv.w;
            sq[i] = x.x * x.x + x.y * x.y + x.z * x.z + x.w * x.w;
            ushort4 h4;
            h4.x = f2h(x.x); h4.y = f2h(x.y); h4.z = f2h(x.z); h4.w = f2h(x.w);
            *(ushort4*)&As[(u >> 6) * 264 + c * 4] = h4;
        }
#pragma unroll
        for (int i = 0; i < 4; ++i) {
#pragma unroll
            for (int o = 32; o; o >>= 1) {
                up[i] += __shfl_down(up[i], o, 64);
                sq[i] += __shfl_down(sq[i], o, 64);
            }
            if (lane == 0) {
                float n1v = sqrtf(fmaxf(sq[i], EPS));
                sgnS[wave + 4 * i] = up[i] + EPS * n1v;
            }
        }
    }
    __syncthreads();

    // (c) GEMM: wave w -> n columns [w*64, w*64+64); A frags shared by waves
    {
        int n0 = wave * 64;
        f16x8 af[8];
#pragma unroll
        for (int ks = 0; ks < 8; ++ks)
            af[ks] = *(const f16x8*)&As[lr * 264 + ks * 32 + lq * 8];
        const unsigned short* gb0 = Gf + (size_t)b * DD + (size_t)(n0 + lr) * D + lq * 8;
#pragma unroll 2
        for (int j = 0; j < 4; ++j) {
            const unsigned short* gb = gb0 + (size_t)(j * 16) * D;
            f32x4 acc = (f32x4){0.f, 0.f, 0.f, 0.f};
#pragma unroll
            for (int ks = 0; ks < 8; ++ks) {
                f16x8 bf = *(const f16x8*)(gb + ks * 32);
                acc = __builtin_amdgcn_mfma_f32_16x16x32_f16(af[ks], bf, acc, 0, 0, 0);
            }
#pragma unroll
            for (int r4 = 0; r4 < 4; ++r4)
                Ms[(lq * 4 + r4) * 264 + n0 + j * 16 + lr] = f2h(acc[r4]);
        }
    }
    __syncthreads();

    // (d) epilogue: wave w -> rows w*4 .. w*4+3
    int dg = lane & 15, ps = lane >> 4;
#pragma unroll 1
    for (int rl = 0; rl < 4; ++rl) {
        int l = wave * 4 + rl;
        float4 sm[4], ss[4], mm[4];
#pragma unroll
        for (int j = 0; j < 4; ++j) {
            ushort4 h4 = *(const ushort4*)&As[l * 264 + dg * 4 + j * 64];
            ushort4 m4 = *(const ushort4*)&Ms[l * 264 + dg * 4 + j * 64];
            float4 sx, mx;
            sx.x = h2f(h4.x); sx.y = h2f(h4.y); sx.z = h2f(h4.z); sx.w = h2f(h4.w);
            mx.x = h2f(m4.x); mx.y = h2f(m4.y); mx.z = h2f(m4.z); mx.w = h2f(m4.w);
            sm[j].x = sx.x * mx.x; sm[j].y = sx.y * mx.y; sm[j].z = sx.z * mx.z; sm[j].w = sx.w * mx.w;
            ss[j].x = sx.x * sx.x; ss[j].y = sx.y * sx.y; ss[j].z = sx.z * sx.z; ss[j].w = sx.w * sx.w;
            mm[j].x = mx.x * mx.x; mm[j].y = mx.y * mx.y; mm[j].z = mx.z * mx.z; mm[j].w = mx.w * mx.w;
        }
        float sgn = (sgnS[l] < 0.f) ? -1.f : 1.f;
#pragma unroll
        for (int tI = 0; tI < 5; ++tI) {
            int p = ps + tI * 4;
            float na = 0.f, nb = 0.f, nc = 0.f;
#pragma unroll
            for (int j = 0; j < 4; ++j) {
                float4 kv = *(const float4*)&k2s[p * 264 + j * 64 + dg * 4];
                na += sm[j].x * kv.x + sm[j].y * kv.y + sm[j].z * kv.z + sm[j].w * kv.w;
                nb += ss[j].x * kv.x + ss[j].y * kv.y + ss[j].z * kv.z + ss[j].w * kv.w;
                nc += mm[j].x * kv.x + mm[j].y * kv.y + mm[j].z * kv.z + mm[j].w * kv.w;
            }
#pragma unroll
            for (int o = 8; o; o >>= 1) {
                na += __shfl_down(na, o, 16);
                nb += __shfl_down(nb, o, 16);
                nc += __shfl_down(nc, o, 16);
            }
            if (dg == 0) {
                out[(size_t)(b * L + l0 + l) * P + p] =
                    sgn * na * rsqrtf(fmaxf(nb, EPS)) * rsqrtf(fmaxf(nc, EPS));
            }
        }
    }
}

extern "C" void kernel_launch(void* const* d_in, const int* in_sizes, int n_in,
                              void* d_out, int out_size, void* d_ws, size_t ws_size,
                              hipStream_t stream) {
    const float* s1   = (const float*)d_in[0];
    const float* s2   = (const float*)d_in[1];
    const float* kern = (const float*)d_in[2];
    float* out = (float*)d_out;
    float* ws  = (float*)d_ws;

    float* tp = ws;                                            // 131072 f
    unsigned short* CT = (unsigned short*)(ws + 131072);       // 4194304 h
    unsigned short* Gf = (unsigned short*)(ws + 2228224);      // 1048576 h

    k_prep2<<<512, 512, 0, stream>>>(s2, tp, CT);
    k_gram32<<<576, 256, 0, stream>>>(CT, Gf);
    k_mav_out<<<1024, 256, 0, stream>>>(s1, tp, Gf, kern, out);
}

// Round 8
// 109.312 us; speedup vs baseline: 1.2272x; 1.1363x over previous
//
#include <hip/hip_runtime.h>
#include <math.h>

#define EPS 1e-7f

constexpr int B = 16, L = 1024, D = 256, P = 20;
constexpr int LD = L * D;     // 262144
constexpr int DD = D * D;     // 65536

typedef __attribute__((ext_vector_type(8))) _Float16 f16x8;
typedef __attribute__((ext_vector_type(4))) float f32x4;

// ---------------------------------------------------------------------------
// ws layout (float slots):
//   tp  @0        131072   fp32 [32][B][D]   t partials
//   CT  @131072   2097152  fp16 [B][D][L]    s2*sqrt(invn2), transposed
//   Gf  @2228224  524288   fp16 [B][D][D]    gram (symmetric)
// Round 8: round 7's MFMA epilogue, with the overflow fixed.  Ms now stores
// u * (1/256) (power-of-two scale: exponent shift only, same fp16 mantissa
// precision; output is scale-invariant in mav).  Round 7 stored unscaled u
// (|u| up to ~400) and squared it IN FP16 in the epilogue: 400^2 > 65504
// -> inf -> absmax 4e5.  With the 1/256 scale: ma<=~2, ma^2<=~4, sa*ma<=~8.
// prep2/gram unchanged from round 6 (verified).
// ---------------------------------------------------------------------------

#define MAV_SCALE 0.00390625f   // 1/256, exact in fp16

__device__ inline unsigned short f2h(float x) {
    _Float16 h = (_Float16)x;
    union { _Float16 h; unsigned short u; } c; c.h = h; return c.u;
}
__device__ inline float h2f(unsigned short u) {
    union { unsigned short u; _Float16 h; } c; c.u = u; return (float)c.h;
}

// K1: one pass over s2.  Block = 32 rows (b, m0..m0+31), 512 threads.
// (unchanged from round 6, verified)
__global__ __launch_bounds__(512) void k_prep2(const float* __restrict__ s2,
                                               float* __restrict__ tp,
                                               unsigned short* __restrict__ CT) {
    __shared__ float tile[32][260];
    __shared__ float wiv[32];
    __shared__ float wsq[32];
    __shared__ float tpp[2][256];
    int tid = threadIdx.x;
    int b   = blockIdx.x >> 5, mt = blockIdx.x & 31;
    int m0  = mt * 32;
    const float* gbase = s2 + (size_t)b * LD + (size_t)m0 * D;
    float4 v[4];
#pragma unroll
    for (int i = 0; i < 4; ++i) {
        int u = tid + i * 512;
        v[i] = *(const float4*)(gbase + (size_t)(u >> 6) * D + (u & 63) * 4);
    }
#pragma unroll
    for (int i = 0; i < 4; ++i) {
        int u = tid + i * 512;
        *(float4*)&tile[u >> 6][(u & 63) * 4] = v[i];
    }
    __syncthreads();
    {
        int r = tid >> 4, seg = tid & 15;
        float s = 0.f;
#pragma unroll
        for (int q = 0; q < 4; ++q) {
            float4 x = *(const float4*)&tile[r][seg * 16 + q * 4];
            s += x.x * x.x + x.y * x.y + x.z * x.z + x.w * x.w;
        }
#pragma unroll
        for (int o = 8; o; o >>= 1) s += __shfl_down(s, o, 16);
        if (seg == 0) {
            float iv = 1.0f / sqrtf(fmaxf(s, EPS));
            wiv[r] = iv;
            wsq[r] = sqrtf(iv);
        }
    }
    __syncthreads();
    {
        int dc = tid & 255, h = tid >> 8;
        float tpart = 0.f;
#pragma unroll
        for (int mm = 0; mm < 16; ++mm) {
            int m = h * 16 + mm;
            tpart += tile[m][dc] * wiv[m];
        }
        tpp[h][dc] = tpart;
    }
    {
        unsigned short* cbase = CT + (size_t)b * LD + m0;
#pragma unroll
        for (int i = 0; i < 2; ++i) {
            int u = tid + i * 512;
            int d = u >> 2, c = u & 3;
            union { unsigned short us[8]; uint4 q; } pk;
#pragma unroll
            for (int k = 0; k < 8; ++k) {
                int m = c * 8 + k;
                pk.us[k] = f2h(tile[m][d] * wsq[m]);
            }
            *(uint4*)(cbase + (size_t)d * L + c * 8) = pk.q;
        }
    }
    __syncthreads();
    if (tid < 256)
        tp[(size_t)(mt * B + b) * D + tid] = tpp[0][tid] + tpp[1][tid];
}

// K2: gram G = C C^T, SYMMETRIC ti<=tj tiles, LDS staging, K-split 4 waves.
// Grid 576.  (unchanged from round 6, verified)
__global__ __launch_bounds__(256) void k_gram32(const unsigned short* __restrict__ CT,
                                                unsigned short* __restrict__ Gf) {
    __shared__ short smem[2 * 32 * 264];
    short* As = smem;
    short* Bs = smem + 32 * 264;
    int tid = threadIdx.x;
    int b   = blockIdx.x / 36;
    int t   = blockIdx.x - b * 36;
    int ti = 0, rem = t;
    while (rem >= 8 - ti) { rem -= 8 - ti; ++ti; }
    int tj = ti + rem;
    bool diag = (ti == tj);
    int wave = tid >> 6, lane = tid & 63;
    int lr = lane & 15, lq = lane >> 4;

    const unsigned short* rowA = CT + (size_t)b * LD + (size_t)(ti * 32) * L;
    const unsigned short* rowB = CT + (size_t)b * LD + (size_t)(tj * 32) * L;

    f32x4 acc[2][2];
#pragma unroll
    for (int i = 0; i < 2; ++i)
#pragma unroll
        for (int j = 0; j < 2; ++j) acc[i][j] = (f32x4){0.f, 0.f, 0.f, 0.f};

#pragma unroll 1
    for (int kb = 0; kb < 4; ++kb) {
        int koff = kb * 256;
        __syncthreads();
        {
#pragma unroll
            for (int i = 0; i < 4; ++i) {
                int u = tid + i * 256;
                int row = u >> 5, c = u & 31;
                *(uint4*)&As[row * 264 + c * 8] =
                    *(const uint4*)(rowA + (size_t)row * L + koff + c * 8);
            }
            if (!diag) {
#pragma unroll
                for (int i = 0; i < 4; ++i) {
                    int u = tid + i * 256;
                    int row = u >> 5, c = u & 31;
                    *(uint4*)&Bs[row * 264 + c * 8] =
                        *(const uint4*)(rowB + (size_t)row * L + koff + c * 8);
                }
            }
        }
        __syncthreads();
        const short* Bp = diag ? As : Bs;
#pragma unroll
        for (int kk = 0; kk < 2; ++kk) {
            int ks = wave * 2 + kk;
            f16x8 af[2], bf[2];
#pragma unroll
            for (int i = 0; i < 2; ++i)
                af[i] = *(const f16x8*)&As[(i * 16 + lr) * 264 + ks * 32 + lq * 8];
#pragma unroll
            for (int j = 0; j < 2; ++j)
                bf[j] = *(const f16x8*)&Bp[(j * 16 + lr) * 264 + ks * 32 + lq * 8];
#pragma unroll
            for (int i = 0; i < 2; ++i)
#pragma unroll
                for (int j = 0; j < 2; ++j)
                    acc[i][j] = __builtin_amdgcn_mfma_f32_16x16x32_f16(af[i], bf[j], acc[i][j], 0, 0, 0);
        }
    }
    __syncthreads();
    float* red = (float*)smem;
#pragma unroll
    for (int i = 0; i < 2; ++i)
#pragma unroll
        for (int j = 0; j < 2; ++j)
#pragma unroll
            for (int r = 0; r < 4; ++r) {
                int row = i * 16 + lq * 4 + r, col = j * 16 + lr;
                red[wave * 1056 + row * 33 + col] = acc[i][j][r];
            }
    __syncthreads();
    unsigned short* gout = Gf + (size_t)b * DD;
#pragma unroll
    for (int k = 0; k < 4; ++k) {
        int e = tid + k * 256;
        int row = e >> 5, col = e & 31;
        float s = red[row * 33 + col] + red[1056 + row * 33 + col] +
                  red[2112 + row * 33 + col] + red[3168 + row * 33 + col];
        gout[(size_t)(ti * 32 + row) * D + tj * 32 + col] = f2h(s);
    }
    if (!diag) {
#pragma unroll
        for (int k = 0; k < 4; ++k) {
            int e = tid + k * 256;
            int r2 = e >> 5, c2 = e & 31;
            float s = red[c2 * 33 + r2] + red[1056 + c2 * 33 + r2] +
                      red[2112 + c2 * 33 + r2] + red[3168 + c2 * 33 + r2];
            gout[(size_t)(tj * 32 + r2) * D + ti * 32 + c2] = f2h(s);
        }
    }
}

// K3: FUSED mav = s1 @ G + MFMA epilogue (no shuffles).
// Block = 32 l rows, 256 threads (4 waves), LDS ~52KB -> 3 blocks/CU.
// Grid = 16 b x 32 lt = 512.
//   a) ts reduce + k2h (fp16 kernel^2, p padded to 32) stage
//   b) s1 -> As fp16 (8 thr/row), sign of (s1.t + EPS*n1)
//   c) GEMM: wave (rowg=w&1, cols (w>>1)*128..+128), B direct from Gf;
//      -> Ms scaled by 1/256 (fp16-overflow headroom for the epilogue)
//   d) epilogue: wave (rowg=w&1, pt=w>>1): A-frags = As*Ms / As*As / Ms*Ms
//      (packed fp16 mul in regs), B-frag = k2h -> 3 MFMA accs; na/nb/nc in
//      same lane/reg -> direct global store.
__global__ __launch_bounds__(256) void k_mav_out(const float* __restrict__ s1,
                                                 const float* __restrict__ tp,
                                                 const unsigned short* __restrict__ Gf,
                                                 const float* __restrict__ kern,
                                                 float* __restrict__ out) {
    __shared__ short As[32 * 264];
    __shared__ short Ms[32 * 264];
    __shared__ short k2h[32 * 264];
    __shared__ float ts[256];
    __shared__ float sgnS[32];
    int tid  = threadIdx.x;
    int b    = blockIdx.x >> 5, lt = blockIdx.x & 31;
    int l0   = lt * 32;
    int wave = tid >> 6, lane = tid & 63;
    int lr   = lane & 15, lq = lane >> 4;

    // (a) ts reduce + k2h stage
    {
        float a = 0.f;
#pragma unroll
        for (int mc = 0; mc < 32; ++mc) a += tp[(size_t)(mc * B + b) * D + tid];
        ts[tid] = a;
    }
#pragma unroll
    for (int p = 0; p < 32; ++p) {
        unsigned short hv = 0;
        if (p < P) {
            float v = kern[p * D + tid];
            hv = f2h(v * v);
        }
        k2h[p * 264 + tid] = hv;
    }
    __syncthreads();

    // (b) s1 -> As fp16; per-row sign of (s1.t + EPS*n1).  8 thr/row.
    {
        int r = tid >> 3, seg = tid & 7;
        const float* gp = s1 + (size_t)(b * L + l0 + r) * D + seg * 32;
        float up = 0.f, sq = 0.f;
        union { unsigned short us[32]; uint4 q[4]; } hb;
#pragma unroll
        for (int q8 = 0; q8 < 8; ++q8) {
            float4 v = ((const float4*)gp)[q8];
            int td = seg * 32 + q8 * 4;
            up += v.x * ts[td] + v.y * ts[td + 1] + v.z * ts[td + 2] + v.w * ts[td + 3];
            sq += v.x * v.x + v.y * v.y + v.z * v.z + v.w * v.w;
            hb.us[q8 * 4 + 0] = f2h(v.x); hb.us[q8 * 4 + 1] = f2h(v.y);
            hb.us[q8 * 4 + 2] = f2h(v.z); hb.us[q8 * 4 + 3] = f2h(v.w);
        }
        short* la = &As[r * 264 + seg * 32];
        ((uint4*)la)[0] = hb.q[0]; ((uint4*)la)[1] = hb.q[1];
        ((uint4*)la)[2] = hb.q[2]; ((uint4*)la)[3] = hb.q[3];
#pragma unroll
        for (int o = 4; o; o >>= 1) { up += __shfl_down(up, o, 8); sq += __shfl_down(sq, o, 8); }
        if (seg == 0) {
            float n1v = sqrtf(fmaxf(sq, EPS));
            sgnS[r] = up + EPS * n1v;          // only the sign is ever used
        }
    }
    __syncthreads();

    // (c) GEMM: wave w -> rowg = w&1 (16 rows), cols c0 = (w>>1)*128
    {
        int rowg = wave & 1;
        int c0   = (wave >> 1) * 128;
        f16x8 af[8];
#pragma unroll
        for (int ks = 0; ks < 8; ++ks)
            af[ks] = *(const f16x8*)&As[(rowg * 16 + lr) * 264 + ks * 32 + lq * 8];
        const unsigned short* gb0 = Gf + (size_t)b * DD + (size_t)(c0 + lr) * D + lq * 8;
#pragma unroll 2
        for (int j = 0; j < 8; ++j) {
            const unsigned short* gb = gb0 + (size_t)(j * 16) * D;
            f32x4 acc = (f32x4){0.f, 0.f, 0.f, 0.f};
#pragma unroll
            for (int ks = 0; ks < 8; ++ks) {
                f16x8 bf = *(const f16x8*)(gb + ks * 32);
                acc = __builtin_amdgcn_mfma_f32_16x16x32_f16(af[ks], bf, acc, 0, 0, 0);
            }
#pragma unroll
            for (int r4 = 0; r4 < 4; ++r4)
                Ms[(rowg * 16 + lq * 4 + r4) * 264 + c0 + j * 16 + lr] =
                    f2h(acc[r4] * MAV_SCALE);
        }
    }
    __syncthreads();

    // (d) MFMA epilogue: wave w -> rowg = w&1, pt = w>>1
    {
        int rowg = wave & 1;
        int pt   = wave >> 1;
        f32x4 ax = (f32x4){0.f, 0.f, 0.f, 0.f};
        f32x4 an = (f32x4){0.f, 0.f, 0.f, 0.f};
        f32x4 am = (f32x4){0.f, 0.f, 0.f, 0.f};
#pragma unroll
        for (int ks = 0; ks < 8; ++ks) {
            f16x8 sa = *(const f16x8*)&As[(rowg * 16 + lr) * 264 + ks * 32 + lq * 8];
            f16x8 ma = *(const f16x8*)&Ms[(rowg * 16 + lr) * 264 + ks * 32 + lq * 8];
            f16x8 bf = *(const f16x8*)&k2h[(pt * 16 + lr) * 264 + ks * 32 + lq * 8];
            f16x8 xa = sa * ma;
            f16x8 s2 = sa * sa;
            f16x8 m2 = ma * ma;
            ax = __builtin_amdgcn_mfma_f32_16x16x32_f16(xa, bf, ax, 0, 0, 0);
            an = __builtin_amdgcn_mfma_f32_16x16x32_f16(s2, bf, an, 0, 0, 0);
            am = __builtin_amdgcn_mfma_f32_16x16x32_f16(m2, bf, am, 0, 0, 0);
        }
        int p = pt * 16 + lr;
        if (p < P) {
#pragma unroll
            for (int r4 = 0; r4 < 4; ++r4) {
                int row = rowg * 16 + lq * 4 + r4;
                float sgn = (sgnS[row] < 0.f) ? -1.f : 1.f;
                out[(size_t)(b * L + l0 + row) * P + p] =
                    sgn * ax[r4] * rsqrtf(fmaxf(an[r4], EPS)) * rsqrtf(fmaxf(am[r4], EPS));
            }
        }
    }
}

extern "C" void kernel_launch(void* const* d_in, const int* in_sizes, int n_in,
                              void* d_out, int out_size, void* d_ws, size_t ws_size,
                              hipStream_t stream) {
    const float* s1   = (const float*)d_in[0];
    const float* s2   = (const float*)d_in[1];
    const float* kern = (const float*)d_in[2];
    float* out = (float*)d_out;
    float* ws  = (float*)d_ws;

    float* tp = ws;                                            // 131072 f
    unsigned short* CT = (unsigned short*)(ws + 131072);       // 4194304 h
    unsigned short* Gf = (unsigned short*)(ws + 2228224);      // 1048576 h

    k_prep2<<<512, 512, 0, stream>>>(s2, tp, CT);
    k_gram32<<<576, 256, 0, stream>>>(CT, Gf);
    k_mav_out<<<512, 256, 0, stream>>>(s1, tp, Gf, kern, out);
}

// Round 10
// 106.482 us; speedup vs baseline: 1.2598x; 1.0266x over previous
//
#include <hip/hip_runtime.h>
#include <math.h>

#define EPS 1e-7f

constexpr int B = 16, L = 1024, D = 256, P = 20;
constexpr int LD = L * D;     // 262144
constexpr int DD = D * D;     // 65536

typedef __attribute__((ext_vector_type(8))) _Float16 f16x8;
typedef __attribute__((ext_vector_type(4))) float f32x4;

// ---------------------------------------------------------------------------
// ws layout (float slots):
//   tp   @0        131072   fp32 [32][B][D]   t partials
//   CT   @131072   2097152  fp16 [B][D][L]    s2*sqrt(invn2), transposed
//   Gf   @2228224  524288   fp16 [B][D][D]    gram (1048576 halves!)
//   tsg  @2752512  4096     fp32 [B][D]       reduced t (AFTER Gf ends)
// Round 10: round 9 with the tsg aliasing fixed.  Round 9 put tsg at
// ws+2490368, INSIDE Gf's float range [2228224, 2752512) -> gram's tail
// overwrote Gf for b>=8 with fp32 bit patterns -> NaN.  tsg now at 2752512.
// All kernel code identical to round 9.
// ---------------------------------------------------------------------------

#define MAV_SCALE 0.00390625f   // 1/256, exact in fp16

__device__ inline unsigned short f2h(float x) {
    _Float16 h = (_Float16)x;
    union { _Float16 h; unsigned short u; } c; c.h = h; return c.u;
}
__device__ inline float h2f(unsigned short u) {
    union { unsigned short u; _Float16 h; } c; c.u = u; return (float)c.h;
}

// K1: one pass over s2.  Block = 32 rows (b, m0..m0+31), 512 threads.
// (unchanged, verified)
__global__ __launch_bounds__(512) void k_prep2(const float* __restrict__ s2,
                                               float* __restrict__ tp,
                                               unsigned short* __restrict__ CT) {
    __shared__ float tile[32][260];
    __shared__ float wiv[32];
    __shared__ float wsq[32];
    __shared__ float tpp[2][256];
    int tid = threadIdx.x;
    int b   = blockIdx.x >> 5, mt = blockIdx.x & 31;
    int m0  = mt * 32;
    const float* gbase = s2 + (size_t)b * LD + (size_t)m0 * D;
    float4 v[4];
#pragma unroll
    for (int i = 0; i < 4; ++i) {
        int u = tid + i * 512;
        v[i] = *(const float4*)(gbase + (size_t)(u >> 6) * D + (u & 63) * 4);
    }
#pragma unroll
    for (int i = 0; i < 4; ++i) {
        int u = tid + i * 512;
        *(float4*)&tile[u >> 6][(u & 63) * 4] = v[i];
    }
    __syncthreads();
    {
        int r = tid >> 4, seg = tid & 15;
        float s = 0.f;
#pragma unroll
        for (int q = 0; q < 4; ++q) {
            float4 x = *(const float4*)&tile[r][seg * 16 + q * 4];
            s += x.x * x.x + x.y * x.y + x.z * x.z + x.w * x.w;
        }
#pragma unroll
        for (int o = 8; o; o >>= 1) s += __shfl_down(s, o, 16);
        if (seg == 0) {
            float iv = 1.0f / sqrtf(fmaxf(s, EPS));
            wiv[r] = iv;
            wsq[r] = sqrtf(iv);
        }
    }
    __syncthreads();
    {
        int dc = tid & 255, h = tid >> 8;
        float tpart = 0.f;
#pragma unroll
        for (int mm = 0; mm < 16; ++mm) {
            int m = h * 16 + mm;
            tpart += tile[m][dc] * wiv[m];
        }
        tpp[h][dc] = tpart;
    }
    {
        unsigned short* cbase = CT + (size_t)b * LD + m0;
#pragma unroll
        for (int i = 0; i < 2; ++i) {
            int u = tid + i * 512;
            int d = u >> 2, c = u & 3;
            union { unsigned short us[8]; uint4 q; } pk;
#pragma unroll
            for (int k = 0; k < 8; ++k) {
                int m = c * 8 + k;
                pk.us[k] = f2h(tile[m][d] * wsq[m]);
            }
            *(uint4*)(cbase + (size_t)d * L + c * 8) = pk.q;
        }
    }
    __syncthreads();
    if (tid < 256)
        tp[(size_t)(mt * B + b) * D + tid] = tpp[0][tid] + tpp[1][tid];
}

// K2: gram G = C C^T, SYMMETRIC ti<=tj tiles, LDS staging, K-split 4 waves.
// Grid 576.  t==0 block additionally reduces tp -> tsg for its b (tail work,
// no LDS, no barrier).  (verified round 6 core)
__global__ __launch_bounds__(256) void k_gram32(const unsigned short* __restrict__ CT,
                                                const float* __restrict__ tp,
                                                unsigned short* __restrict__ Gf,
                                                float* __restrict__ tsg) {
    __shared__ short smem[2 * 32 * 264];
    short* As = smem;
    short* Bs = smem + 32 * 264;
    int tid = threadIdx.x;
    int b   = blockIdx.x / 36;
    int t   = blockIdx.x - b * 36;
    int ti = 0, rem = t;
    while (rem >= 8 - ti) { rem -= 8 - ti; ++ti; }
    int tj = ti + rem;
    bool diag = (ti == tj);
    int wave = tid >> 6, lane = tid & 63;
    int lr = lane & 15, lq = lane >> 4;

    const unsigned short* rowA = CT + (size_t)b * LD + (size_t)(ti * 32) * L;
    const unsigned short* rowB = CT + (size_t)b * LD + (size_t)(tj * 32) * L;

    f32x4 acc[2][2];
#pragma unroll
    for (int i = 0; i < 2; ++i)
#pragma unroll
        for (int j = 0; j < 2; ++j) acc[i][j] = (f32x4){0.f, 0.f, 0.f, 0.f};

#pragma unroll 1
    for (int kb = 0; kb < 4; ++kb) {
        int koff = kb * 256;
        __syncthreads();
        {
#pragma unroll
            for (int i = 0; i < 4; ++i) {
                int u = tid + i * 256;
                int row = u >> 5, c = u & 31;
                *(uint4*)&As[row * 264 + c * 8] =
                    *(const uint4*)(rowA + (size_t)row * L + koff + c * 8);
            }
            if (!diag) {
#pragma unroll
                for (int i = 0; i < 4; ++i) {
                    int u = tid + i * 256;
                    int row = u >> 5, c = u & 31;
                    *(uint4*)&Bs[row * 264 + c * 8] =
                        *(const uint4*)(rowB + (size_t)row * L + koff + c * 8);
                }
            }
        }
        __syncthreads();
        const short* Bp = diag ? As : Bs;
#pragma unroll
        for (int kk = 0; kk < 2; ++kk) {
            int ks = wave * 2 + kk;
            f16x8 af[2], bf[2];
#pragma unroll
            for (int i = 0; i < 2; ++i)
                af[i] = *(const f16x8*)&As[(i * 16 + lr) * 264 + ks * 32 + lq * 8];
#pragma unroll
            for (int j = 0; j < 2; ++j)
                bf[j] = *(const f16x8*)&Bp[(j * 16 + lr) * 264 + ks * 32 + lq * 8];
#pragma unroll
            for (int i = 0; i < 2; ++i)
#pragma unroll
                for (int j = 0; j < 2; ++j)
                    acc[i][j] = __builtin_amdgcn_mfma_f32_16x16x32_f16(af[i], bf[j], acc[i][j], 0, 0, 0);
        }
    }
    __syncthreads();
    float* red = (float*)smem;
#pragma unroll
    for (int i = 0; i < 2; ++i)
#pragma unroll
        for (int j = 0; j < 2; ++j)
#pragma unroll
            for (int r = 0; r < 4; ++r) {
                int row = i * 16 + lq * 4 + r, col = j * 16 + lr;
                red[wave * 1056 + row * 33 + col] = acc[i][j][r];
            }
    __syncthreads();
    unsigned short* gout = Gf + (size_t)b * DD;
#pragma unroll
    for (int k = 0; k < 4; ++k) {
        int e = tid + k * 256;
        int row = e >> 5, col = e & 31;
        float s = red[row * 33 + col] + red[1056 + row * 33 + col] +
                  red[2112 + row * 33 + col] + red[3168 + row * 33 + col];
        gout[(size_t)(ti * 32 + row) * D + tj * 32 + col] = f2h(s);
    }
    if (!diag) {
#pragma unroll
        for (int k = 0; k < 4; ++k) {
            int e = tid + k * 256;
            int r2 = e >> 5, c2 = e & 31;
            float s = red[c2 * 33 + r2] + red[1056 + c2 * 33 + r2] +
                      red[2112 + c2 * 33 + r2] + red[3168 + c2 * 33 + r2];
            gout[(size_t)(tj * 32 + r2) * D + ti * 32 + c2] = f2h(s);
        }
    }
    // tail: one block per b reduces tp -> tsg (same fp32 sum order as before)
    if (t == 0) {
        float a = 0.f;
#pragma unroll
        for (int mc = 0; mc < 32; ++mc) a += tp[(size_t)(mc * B + b) * D + tid];
        tsg[b * 256 + tid] = a;
    }
}

// K3: FUSED mav = s1 @ G + MFMA epilogue (no shuffles).
// Block = 32 l rows, 256 threads (4 waves), LDS ~52KB.  Grid 512.
// s1 loads issued at kernel entry; ts from precomputed tsg.
__global__ __launch_bounds__(256) void k_mav_out(const float* __restrict__ s1,
                                                 const float* __restrict__ tsg,
                                                 const unsigned short* __restrict__ Gf,
                                                 const float* __restrict__ kern,
                                                 float* __restrict__ out) {
    __shared__ short As[32 * 264];
    __shared__ short Ms[32 * 264];
    __shared__ short k2h[32 * 264];
    __shared__ float ts[256];
    __shared__ float sgnS[32];
    int tid  = threadIdx.x;
    int b    = blockIdx.x >> 5, lt = blockIdx.x & 31;
    int l0   = lt * 32;
    int wave = tid >> 6, lane = tid & 63;
    int lr   = lane & 15, lq = lane >> 4;

    // (0) issue s1 loads NOW; consumed after the staging barrier
    int r = tid >> 3, seg = tid & 7;
    const float* gp = s1 + (size_t)(b * L + l0 + r) * D + seg * 32;
    float4 v8[8];
#pragma unroll
    for (int q8 = 0; q8 < 8; ++q8) v8[q8] = ((const float4*)gp)[q8];

    // (a) ts load + k2h stage
    ts[tid] = tsg[b * 256 + tid];
#pragma unroll
    for (int p = 0; p < 32; ++p) {
        unsigned short hv = 0;
        if (p < P) {
            float v = kern[p * D + tid];
            hv = f2h(v * v);
        }
        k2h[p * 264 + tid] = hv;
    }
    __syncthreads();

    // (b) s1 -> As fp16; per-row sign of (s1.t + EPS*n1).  8 thr/row.
    {
        float up = 0.f, sq = 0.f;
        union { unsigned short us[32]; uint4 q[4]; } hb;
#pragma unroll
        for (int q8 = 0; q8 < 8; ++q8) {
            float4 v = v8[q8];
            int td = seg * 32 + q8 * 4;
            up += v.x * ts[td] + v.y * ts[td + 1] + v.z * ts[td + 2] + v.w * ts[td + 3];
            sq += v.x * v.x + v.y * v.y + v.z * v.z + v.w * v.w;
            hb.us[q8 * 4 + 0] = f2h(v.x); hb.us[q8 * 4 + 1] = f2h(v.y);
            hb.us[q8 * 4 + 2] = f2h(v.z); hb.us[q8 * 4 + 3] = f2h(v.w);
        }
        short* la = &As[r * 264 + seg * 32];
        ((uint4*)la)[0] = hb.q[0]; ((uint4*)la)[1] = hb.q[1];
        ((uint4*)la)[2] = hb.q[2]; ((uint4*)la)[3] = hb.q[3];
#pragma unroll
        for (int o = 4; o; o >>= 1) { up += __shfl_down(up, o, 8); sq += __shfl_down(sq, o, 8); }
        if (seg == 0) {
            float n1v = sqrtf(fmaxf(sq, EPS));
            sgnS[r] = up + EPS * n1v;          // only the sign is ever used
        }
    }
    __syncthreads();

    // (c) GEMM: wave w -> rowg = w&1 (16 rows), cols c0 = (w>>1)*128
    {
        int rowg = wave & 1;
        int c0   = (wave >> 1) * 128;
        f16x8 af[8];
#pragma unroll
        for (int ks = 0; ks < 8; ++ks)
            af[ks] = *(const f16x8*)&As[(rowg * 16 + lr) * 264 + ks * 32 + lq * 8];
        const unsigned short* gb0 = Gf + (size_t)b * DD + (size_t)(c0 + lr) * D + lq * 8;
#pragma unroll 2
        for (int j = 0; j < 8; ++j) {
            const unsigned short* gb = gb0 + (size_t)(j * 16) * D;
            f32x4 acc = (f32x4){0.f, 0.f, 0.f, 0.f};
#pragma unroll
            for (int ks = 0; ks < 8; ++ks) {
                f16x8 bf = *(const f16x8*)(gb + ks * 32);
                acc = __builtin_amdgcn_mfma_f32_16x16x32_f16(af[ks], bf, acc, 0, 0, 0);
            }
#pragma unroll
            for (int r4 = 0; r4 < 4; ++r4)
                Ms[(rowg * 16 + lq * 4 + r4) * 264 + c0 + j * 16 + lr] =
                    f2h(acc[r4] * MAV_SCALE);
        }
    }
    __syncthreads();

    // (d) MFMA epilogue: wave w -> rowg = w&1, pt = w>>1
    {
        int rowg = wave & 1;
        int pt   = wave >> 1;
        f32x4 ax = (f32x4){0.f, 0.f, 0.f, 0.f};
        f32x4 an = (f32x4){0.f, 0.f, 0.f, 0.f};
        f32x4 am = (f32x4){0.f, 0.f, 0.f, 0.f};
#pragma unroll
        for (int ks = 0; ks < 8; ++ks) {
            f16x8 sa = *(const f16x8*)&As[(rowg * 16 + lr) * 264 + ks * 32 + lq * 8];
            f16x8 ma = *(const f16x8*)&Ms[(rowg * 16 + lr) * 264 + ks * 32 + lq * 8];
            f16x8 bf = *(const f16x8*)&k2h[(pt * 16 + lr) * 264 + ks * 32 + lq * 8];
            f16x8 xa = sa * ma;
            f16x8 s2 = sa * sa;
            f16x8 m2 = ma * ma;
            ax = __builtin_amdgcn_mfma_f32_16x16x32_f16(xa, bf, ax, 0, 0, 0);
            an = __builtin_amdgcn_mfma_f32_16x16x32_f16(s2, bf, an, 0, 0, 0);
            am = __builtin_amdgcn_mfma_f32_16x16x32_f16(m2, bf, am, 0, 0, 0);
        }
        int p = pt * 16 + lr;
        if (p < P) {
#pragma unroll
            for (int r4 = 0; r4 < 4; ++r4) {
                int row = rowg * 16 + lq * 4 + r4;
                float sgn = (sgnS[row] < 0.f) ? -1.f : 1.f;
                out[(size_t)(b * L + l0 + row) * P + p] =
                    sgn * ax[r4] * rsqrtf(fmaxf(an[r4], EPS)) * rsqrtf(fmaxf(am[r4], EPS));
            }
        }
    }
}

extern "C" void kernel_launch(void* const* d_in, const int* in_sizes, int n_in,
                              void* d_out, int out_size, void* d_ws, size_t ws_size,
                              hipStream_t stream) {
    const float* s1   = (const float*)d_in[0];
    const float* s2   = (const float*)d_in[1];
    const float* kern = (const float*)d_in[2];
    float* out = (float*)d_out;
    float* ws  = (float*)d_ws;

    float* tp = ws;                                            // 131072 f
    unsigned short* CT = (unsigned short*)(ws + 131072);       // 4194304 h
    unsigned short* Gf = (unsigned short*)(ws + 2228224);      // 1048576 h -> ends @2752512 f
    float* tsg = ws + 2752512;                                 // 4096 f (after Gf!)

    k_prep2<<<512, 512, 0, stream>>>(s2, tp, CT);
    k_gram32<<<576, 256, 0, stream>>>(CT, tp, Gf, tsg);
    k_mav_out<<<512, 256, 0, stream>>>(s1, tsg, Gf, kern, out);
}